// Round 14
// baseline (89.818 us; speedup 1.0000x reference)
//
#include <hip/hip_runtime.h>

#define N2 4096
#define D 128
#define TAU_INV 10.0f
#define E2SCALE 14.4269504088896340736f   // 10 * log2(e): exp(10x) = exp2(x*E2SCALE)
#define BM 256                    // i-rows per GEMM block (8 waves x 32)
#define BN 256                    // j-cols per GEMM block (8 tiles, LDS-staged)
#define NT (BN / 32)              // 8
#define NIT (N2 / BM)             // 16
#define GEMM_BLOCKS (NIT * NIT)   // 256
#define NCLS 10
#define CGRP 16
#define CROWS (N2 / CGRP)         // 256 rows per class block
#define CB (NCLS * CGRP)          // 160 class blocks
#define PCW 130                   // per-class-block partial width: S[128],T,CNT

typedef __attribute__((ext_vector_type(8))) short bf16x8;
typedef __attribute__((ext_vector_type(16))) float floatx16;

__device__ __forceinline__ short f2bf(float f) {
    unsigned u = __float_as_uint(f);
    u = (u + 0x7fff + ((u >> 16) & 1)) >> 16;   // RNE
    return (short)u;
}
__device__ __forceinline__ float bf2f(short s) {
    return __uint_as_float(((unsigned)(unsigned short)s) << 16);
}

// ONE fused kernel: 256 GEMM blocks + 160 class blocks. No prep dispatch:
// each block normalizes the rows it needs from zi/zj directly (identical op
// sequence to the old prep: f2bf(v * (1.0f/sqrtf(ssq)))). No atomics anywhere:
// GEMM blocks PLAIN-STORE per-row 256-col partial exp-sums to pse[row][js];
// class blocks plain-store per-block S/T/CNT partials. Nothing needs zero-init
// -> no memset node. Grid: 3 nodes total (harness fill + this + finish).
//
// GEMM block (it,js): B-range (js*256..+256) normalized into 64KB LDS chunk-
// major by a quad-per-row pass; A-range per-wave into registers (lane owns the
// 64 dims of row rbase+col it needs; full-row ssq via shfl_xor(.,32) with the
// other half-lane). K-loop = r13's: MFMA 32x32x16, K=128, B from ds_read.
// C/D: col=lane&31, row=(reg&3)+8*(reg>>2)+4*(lane>>5). Diagonal tile
// (j0==rbase) wave-uniform; self-pair excluded exactly as before.
//
// Class block cb (class c, group g): wave-per-row inline normalize, masked
// accumulate (labels used as VALUES only; all addresses structural).
__global__ __launch_bounds__(512) void main_kernel(const float* __restrict__ zi,
                                                   const float* __restrict__ zj,
                                                   const long long* __restrict__ y,
                                                   float* __restrict__ pse,
                                                   float* __restrict__ pcls) {
    __shared__ short ldsB[BN * D];          // 64 KB (class path reuses as float*)
    int tid = threadIdx.x;
    int wave = tid >> 6;
    int lane = tid & 63;

    if (blockIdx.x >= GEMM_BLOCKS) {
        // ---- class-sum path ----
        float* shf = (float*)ldsB;          // [0,1024): S by wave; [1024,1032): T; [1032,1040): cnt
        int cb = blockIdx.x - GEMM_BLOCKS;  // 0..159
        int c  = cb / CGRP;
        int g  = cb % CGRP;

        float sSx = 0.f, sSy = 0.f, sT = 0.f, cnt = 0.f;
        for (int i = 0; i < CROWS / 8; ++i) {        // 32 rows per wave
            int r = g * CROWS + wave * (CROWS / 8) + i;
            const float* src = (r < 2048) ? (zi + r * D) : (zj + (r - 2048) * D);
            float2 v = ((const float2*)src)[lane];
            float ss = v.x * v.x + v.y * v.y;
            #pragma unroll
            for (int m = 1; m < 64; m <<= 1) ss += __shfl_xor(ss, m);
            float inv = 1.0f / sqrtf(ss);
            float qx = bf2f(f2bf(v.x * inv));
            float qy = bf2f(f2bf(v.y * inv));
            bool m = ((int)y[r & 2047] == c);        // wave-uniform
            sSx += m ? qx : 0.f;
            sSy += m ? qy : 0.f;
            sT  += m ? (qx * qx + qy * qy) : 0.f;
            cnt += m ? 1.f : 0.f;                    // identical across lanes
        }
        shf[wave * D + 2 * lane]     = sSx;
        shf[wave * D + 2 * lane + 1] = sSy;
        #pragma unroll
        for (int m = 1; m < 64; m <<= 1) sT += __shfl_xor(sT, m);
        if (lane == 0) { shf[1024 + wave] = sT; shf[1032 + wave] = cnt; }
        __syncthreads();
        if (tid < D) {
            float s = 0.f;
            #pragma unroll
            for (int w = 0; w < 8; ++w) s += shf[w * D + tid];
            pcls[cb * PCW + tid] = s;
        } else if (tid == D) {
            float s = 0.f;
            #pragma unroll
            for (int w = 0; w < 8; ++w) s += shf[1024 + w];
            pcls[cb * PCW + 128] = s;
        } else if (tid == D + 1) {
            float s = 0.f;
            #pragma unroll
            for (int w = 0; w < 8; ++w) s += shf[1032 + w];
            pcls[cb * PCW + 129] = s;
        }
        return;
    }

    // ---- GEMM path ----
    int gb = blockIdx.x;
    int col  = lane & 31;
    int half = lane >> 5;
    int it = gb >> 4;                  // 0..15
    int js = gb & 15;                  // 0..15
    int rbase = it * BM + wave * 32;

    // stage B-range into LDS chunk-major: 2 passes x (128 rows, 4 threads/row)
    #pragma unroll
    for (int pass = 0; pass < 2; ++pass) {
        int rl = pass * 128 + (tid >> 2);           // 0..255 row within range
        int q  = tid & 3;                           // dim quarter: d0 = q*32
        int gr = js * BN + rl;
        const float* srcb = (gr < 2048) ? (zi + gr * D) : (zj + (gr - 2048) * D);
        float4 b0[8];
        float part = 0.f;
        #pragma unroll
        for (int j = 0; j < 8; ++j) {
            float4 u = *(const float4*)(srcb + q * 32 + j * 4);
            part += u.x * u.x + u.y * u.y + u.z * u.z + u.w * u.w;
            b0[j] = u;
        }
        part += __shfl_xor(part, 1);
        part += __shfl_xor(part, 2);                // quad sum = full-row ssq
        float invb = 1.0f / sqrtf(part);
        #pragma unroll
        for (int jj = 0; jj < 4; ++jj) {
            float4 u = b0[2 * jj], v = b0[2 * jj + 1];
            bf16x8 t;
            t[0] = f2bf(u.x * invb); t[1] = f2bf(u.y * invb);
            t[2] = f2bf(u.z * invb); t[3] = f2bf(u.w * invb);
            t[4] = f2bf(v.x * invb); t[5] = f2bf(v.y * invb);
            t[6] = f2bf(v.z * invb); t[7] = f2bf(v.w * invb);
            // chunk kk = q*4+jj holds dims kk*8..kk*8+8 of row rl
            *(bf16x8*)&ldsB[(rl >> 5) * 4096 + (q * 4 + jj) * 256 + (rl & 31) * 8] = t;
        }
    }

    // A fragments in registers: lane owns dims {k*16+half*8..+8} of row rbase+col
    bf16x8 af[8];
    {
        int grow = rbase + col;                     // 32-row aligned: wave-uniform side
        const float* srca = (grow < 2048) ? (zi + grow * D) : (zj + (grow - 2048) * D);
        float4 a0[8], a1[8];
        float ssq = 0.f;
        #pragma unroll
        for (int k = 0; k < 8; ++k) {
            float4 u = *(const float4*)(srca + k * 16 + half * 8);
            float4 v = *(const float4*)(srca + k * 16 + half * 8 + 4);
            ssq += u.x * u.x + u.y * u.y + u.z * u.z + u.w * u.w
                 + v.x * v.x + v.y * v.y + v.z * v.z + v.w * v.w;
            a0[k] = u; a1[k] = v;
        }
        ssq += __shfl_xor(ssq, 32);                 // other half-lane has same row
        float inv = 1.0f / sqrtf(ssq);
        #pragma unroll
        for (int k = 0; k < 8; ++k) {
            bf16x8 t;
            t[0] = f2bf(a0[k].x * inv); t[1] = f2bf(a0[k].y * inv);
            t[2] = f2bf(a0[k].z * inv); t[3] = f2bf(a0[k].w * inv);
            t[4] = f2bf(a1[k].x * inv); t[5] = f2bf(a1[k].y * inv);
            t[6] = f2bf(a1[k].z * inv); t[7] = f2bf(a1[k].w * inv);
            af[k] = t;
        }
    }

    float se[16];
    #pragma unroll
    for (int r = 0; r < 16; ++r) se[r] = 0.f;

    __syncthreads();                   // B staged

    const bf16x8* lb = (const bf16x8*)ldsB;
    #pragma unroll
    for (int t = 0; t < NT; ++t) {
        int j0 = js * BN + t * 32;

        floatx16 acc;
        #pragma unroll
        for (int r = 0; r < 16; ++r) acc[r] = 0.f;
        #pragma unroll
        for (int k = 0; k < 8; ++k)
            acc = __builtin_amdgcn_mfma_f32_32x32x16_bf16(
                af[k], lb[t * 512 + k * 64 + lane], acc, 0, 0, 0);

        if (j0 == rbase) {                    // wave-uniform: diagonal tile
            int jcol = j0 + col;
            #pragma unroll
            for (int r = 0; r < 16; ++r) {
                int rowr = rbase + (r & 3) + 8 * (r >> 2) + 4 * half;
                float e = __builtin_amdgcn_exp2f(acc[r] * E2SCALE);
                se[r] += (rowr == jcol) ? 0.f : e;
            }
        } else {
            #pragma unroll
            for (int r = 0; r < 16; ++r)
                se[r] += __builtin_amdgcn_exp2f(acc[r] * E2SCALE);
        }
    }

    // reduce over 32 cols; PLAIN STORE this block's 256-col partial per row
    #pragma unroll
    for (int r = 0; r < 16; ++r) {
        float a = se[r];
        #pragma unroll
        for (int m = 1; m < 32; m <<= 1) a += __shfl_xor(a, m);
        if (col == 0) {
            int rowr = rbase + (r & 3) + 8 * (r >> 2) + 4 * half;
            pse[rowr * NIT + js] = a;         // unique (row, js) writer
        }
    }
}

// loss = (sum_i log(sum_js pse[i][js])  -  sum_c 10*(||S_c||^2 - T_c)/(n_c-1)) / N2
__global__ __launch_bounds__(512) void finish_kernel(const float* __restrict__ pse,
                                                     const float* __restrict__ pcls,
                                                     float* __restrict__ out) {
    __shared__ float red[16];
    int tid = threadIdx.x;
    int wave = tid >> 6;
    int lane = tid & 63;

    // denominator: sum 16 j-partials per row (64B contiguous), log, reduce
    float L = 0.f;
    for (int r = tid; r < N2; r += 512) {
        float s = 0.f;
        #pragma unroll
        for (int js = 0; js < NIT; ++js) s += pse[r * NIT + js];
        L += __logf(s);
    }
    #pragma unroll
    for (int m = 1; m < 64; m <<= 1) L += __shfl_xor(L, m);

    // positive-pair term: wave w handles class w (and 8+w for w<2)
    float P = 0.f;
    for (int c = wave; c < NCLS; c += 8) {
        float Sx = 0.f, Sy = 0.f, T = 0.f, n = 0.f;
        #pragma unroll
        for (int g = 0; g < CGRP; ++g) {
            const float* p = pcls + (c * CGRP + g) * PCW;
            Sx += p[2 * lane];
            Sy += p[2 * lane + 1];
            T  += p[128];
            n  += p[129];
        }
        float s2 = Sx * Sx + Sy * Sy;
        #pragma unroll
        for (int m = 1; m < 64; m <<= 1) s2 += __shfl_xor(s2, m);
        P += (n >= 2.0f) ? (s2 - T) * TAU_INV / (n - 1.0f) : 0.f;
    }

    if (lane == 0) { red[wave] = L; red[8 + wave] = P; }
    __syncthreads();
    if (tid == 0) {
        float Ls = 0.f, Ps = 0.f;
        #pragma unroll
        for (int w = 0; w < 8; ++w) { Ls += red[w]; Ps += red[8 + w]; }
        out[0] = (Ls - Ps) * (1.0f / (float)N2);
    }
}

extern "C" void kernel_launch(void* const* d_in, const int* in_sizes, int n_in,
                              void* d_out, int out_size, void* d_ws, size_t ws_size,
                              hipStream_t stream) {
    const float*     zi = (const float*)d_in[0];
    const float*     zj = (const float*)d_in[1];
    const long long* y  = (const long long*)d_in[2];
    float* out = (float*)d_out;

    char* ws = (char*)d_ws;
    float* pse  = (float*)ws;                      // 4096*16 f32 = 256 KB (no init needed)
    float* pcls = pse + N2 * NIT;                  // 160*130 f32 = 83 KB (no init needed)

    main_kernel<<<GEMM_BLOCKS + CB, 512, 0, stream>>>(zi, zj, y, pse, pcls);
    finish_kernel<<<1, 512, 0, stream>>>(pse, pcls, out);
}